// Round 1
// baseline (2854.037 us; speedup 1.0000x reference)
//
#include <hip/hip_runtime.h>
#include <math.h>

// Problem constants
#define NROWS 8192
#define DDAT  784
#define DLAT  64
#define NTILE 64          // tile rows/cols per block
#define NB    (NROWS / NTILE)   // 128 blocks per dim
#define NPART (NB * NB)         // 16384 partial slots per matrix

// ---------------------------------------------------------------------------
// Row squared-norms for all three inputs. grid = (8192, 3), block = 256.
// ---------------------------------------------------------------------------
__global__ void rownorm_kernel(const float* __restrict__ dat,
                               const float* __restrict__ rec,
                               const float* __restrict__ z,
                               float* __restrict__ o_dat,
                               float* __restrict__ o_rec,
                               float* __restrict__ o_z)
{
    const float* X; float* O; int D;
    if (blockIdx.y == 0)      { X = dat; O = o_dat; D = DDAT; }
    else if (blockIdx.y == 1) { X = rec; O = o_rec; D = DDAT; }
    else                      { X = z;   O = o_z;   D = DLAT; }

    int row = blockIdx.x;
    float s = 0.f;
    for (int k = threadIdx.x; k < D; k += 256) {
        float v = X[(size_t)row * D + k];
        s += v * v;
    }
    __shared__ float sm[256];
    sm[threadIdx.x] = s;
    __syncthreads();
    for (int off = 128; off > 0; off >>= 1) {
        if (threadIdx.x < off) sm[threadIdx.x] += sm[threadIdx.x + off];
        __syncthreads();
    }
    if (threadIdx.x == 0) O[row] = sm[0];
}

// ---------------------------------------------------------------------------
// Pairwise sum of rsqrt(alpha + beta * ||a_i - b_j||^2) over a 64x64 tile.
// grid = (128,128), block = 256 (logical 16x16, 4x4 microtile per thread).
// sym=1: only bx>=by blocks run; off-diagonal contributions doubled.
// Per-block partial written to part[bid] (pre-zeroed).
// ---------------------------------------------------------------------------
__global__ void pairsum_kernel(const float* __restrict__ A,
                               const float* __restrict__ B,
                               const float* __restrict__ a2,
                               const float* __restrict__ b2,
                               int D, float alpha, float beta, int sym,
                               double* __restrict__ part)
{
    const int bx = blockIdx.x;   // j tile
    const int by = blockIdx.y;   // i tile
    if (sym && bx < by) return;  // slot stays zero

    const int t  = threadIdx.x;
    const int tx = t & 15;
    const int ty = t >> 4;

    // LDS staged transposed: [k][row] so the 4 consecutive rows per thread
    // are a contiguous float4 (ds_read_b128). Pad row stride to 68.
    __shared__ float As[16][68];
    __shared__ float Bs[16][68];

    const int i0 = by * NTILE;
    const int j0 = bx * NTILE;

    float acc[4][4] = {};

    const int lr = t >> 2;        // 0..63: row within tile
    const int lc = (t & 3) * 4;   // 0,4,8,12: col within K-chunk

    for (int k0 = 0; k0 < D; k0 += 16) {
        float4 av = *reinterpret_cast<const float4*>(&A[(size_t)(i0 + lr) * D + k0 + lc]);
        float4 bv = *reinterpret_cast<const float4*>(&B[(size_t)(j0 + lr) * D + k0 + lc]);
        __syncthreads();
        As[lc + 0][lr] = av.x; As[lc + 1][lr] = av.y;
        As[lc + 2][lr] = av.z; As[lc + 3][lr] = av.w;
        Bs[lc + 0][lr] = bv.x; Bs[lc + 1][lr] = bv.y;
        Bs[lc + 2][lr] = bv.z; Bs[lc + 3][lr] = bv.w;
        __syncthreads();

#pragma unroll
        for (int kk = 0; kk < 16; ++kk) {
            float ar[4], br[4];
            *reinterpret_cast<float4*>(ar) = *reinterpret_cast<const float4*>(&As[kk][ty * 4]);
            *reinterpret_cast<float4*>(br) = *reinterpret_cast<const float4*>(&Bs[kk][tx * 4]);
#pragma unroll
            for (int m = 0; m < 4; ++m)
#pragma unroll
                for (int n = 0; n < 4; ++n)
                    acc[m][n] += ar[m] * br[n];
        }
    }

    float lsum = 0.f;
#pragma unroll
    for (int m = 0; m < 4; ++m) {
#pragma unroll
        for (int n = 0; n < 4; ++n) {
            int i = i0 + ty * 4 + m;
            int j = j0 + tx * 4 + n;
            float d = a2[i] + b2[j] - 2.f * acc[m][n];
            d = fmaxf(d, 0.f);
            float x = alpha + beta * d;
            float r = __frsqrt_rn(x);                 // if not exact, Newton below fixes it
            r = r * (1.5f - 0.5f * x * r * r);        // one Newton step for safety
            lsum += r;
        }
    }
    if (sym && bx > by) lsum *= 2.f;   // upper off-diagonal counts twice

    __shared__ float red[256];
    red[t] = lsum;
    __syncthreads();
    for (int off = 128; off > 0; off >>= 1) {
        if (t < off) red[t] += red[t + off];
        __syncthreads();
    }
    if (t == 0) part[(size_t)by * gridDim.x + bx] = (double)red[0];
}

// ---------------------------------------------------------------------------
// Final reduction + scalar math. One block of 256 threads.
// parts: 4 arrays of NPART doubles (dd, rr, dr, zz). z2: 8192 row norms of z.
// ---------------------------------------------------------------------------
__global__ void finalize_kernel(const double* __restrict__ parts,
                                const float* __restrict__ z2,
                                float* __restrict__ out)
{
    const int tid = threadIdx.x;
    double s0 = 0, s1 = 0, s2 = 0, s3 = 0, s4 = 0;
    for (int i = tid; i < NPART; i += 256) {
        s0 += parts[i];
        s1 += parts[NPART + i];
        s2 += parts[2 * NPART + i];
        s3 += parts[3 * NPART + i];
    }
    for (int i = tid; i < NROWS; i += 256) s4 += (double)z2[i];

    __shared__ double sm[256];
    double tot[5];
    double loc[5] = { s0, s1, s2, s3, s4 };
    for (int j = 0; j < 5; ++j) {
        sm[tid] = loc[j];
        __syncthreads();
        for (int off = 128; off > 0; off >>= 1) {
            if (tid < off) sm[tid] += sm[tid + off];
            __syncthreads();
        }
        tot[j] = sm[0];
        __syncthreads();
    }

    if (tid == 0) {
        const double Nn = (double)NROWS;
        const double n2 = Nn * Nn;
        const double y  = pow(4.0 / (3.0 * Nn), 0.4);

        double A = tot[0] / n2;
        double B = tot[1] / n2;
        double C = tot[2] / n2;
        double T = 1.0 / (2.0 * sqrt(M_PI * y));
        double loss_rec = log(T * (A + B - 2.0 * C));

        double An = tot[3] / n2;
        double B1 = tot[4];
        double Bn = 2.0 / sqrt(y + 0.5 + B1 / 125.0);
        double loss_norm = log(1.0 / sqrt(1.0 + y) + An - Bn);

        out[0] = (float)(loss_rec + loss_norm);
    }
}

// ---------------------------------------------------------------------------
extern "C" void kernel_launch(void* const* d_in, const int* in_sizes, int n_in,
                              void* d_out, int out_size, void* d_ws, size_t ws_size,
                              hipStream_t stream)
{
    const float* data = (const float*)d_in[0];
    const float* rec  = (const float*)d_in[1];
    const float* z    = (const float*)d_in[2];
    float* out = (float*)d_out;

    char* ws = (char*)d_ws;
    double* parts = (double*)ws;                         // 4 * NPART doubles
    float*  a2d   = (float*)(ws + 4 * (size_t)NPART * sizeof(double));
    float*  a2r   = a2d + NROWS;
    float*  a2z   = a2r + NROWS;

    hipMemsetAsync(parts, 0, 4 * (size_t)NPART * sizeof(double), stream);

    rownorm_kernel<<<dim3(NROWS, 3), 256, 0, stream>>>(data, rec, z, a2d, a2r, a2z);

    const double y = pow(4.0 / (3.0 * (double)NROWS), 0.4);
    const float beta_s = (float)(1.0 / (1565.0 * y));    // 2*DDAT-3 = 1565

    dim3 grid(NB, NB);
    // A: data-data (symmetric)
    pairsum_kernel<<<grid, 256, 0, stream>>>(data, data, a2d, a2d, DDAT, 1.0f, beta_s, 1, parts);
    // B: recon-recon (symmetric)
    pairsum_kernel<<<grid, 256, 0, stream>>>(rec, rec, a2r, a2r, DDAT, 1.0f, beta_s, 1, parts + NPART);
    // C: data-recon (full)
    pairsum_kernel<<<grid, 256, 0, stream>>>(data, rec, a2d, a2r, DDAT, 1.0f, beta_s, 0, parts + 2 * NPART);
    // normality: z-z (symmetric), val = rsqrt(y + dist/125)
    pairsum_kernel<<<grid, 256, 0, stream>>>(z, z, a2z, a2z, DLAT, (float)y, 1.0f / 125.0f, 1, parts + 3 * NPART);

    finalize_kernel<<<1, 256, 0, stream>>>(parts, a2z, out);
}

// Round 3
// 529.467 us; speedup vs baseline: 5.3904x; 5.3904x over previous
//
#include <hip/hip_runtime.h>
#include <hip/hip_bf16.h>
#include <math.h>

// Problem constants
#define NROWS 8192
#define DDAT  784
#define DLAT  64
#define TILE  128            // output tile per block
#define NBT   (NROWS / TILE) // 64 tiles per dim
#define NPARTS (NBT * NBT)   // 4096 partial slots per matrix

typedef __attribute__((ext_vector_type(8))) short bf16x8;
typedef __attribute__((ext_vector_type(4))) float f32x4;

// ---------------------------------------------------------------------------
// Row squared-norms (fp32 exact). grid = (8192, 3), block = 256.
// (verbatim from round-1 passing kernel)
// ---------------------------------------------------------------------------
__global__ void rownorm_kernel(const float* __restrict__ dat,
                               const float* __restrict__ rec,
                               const float* __restrict__ z,
                               float* __restrict__ o_dat,
                               float* __restrict__ o_rec,
                               float* __restrict__ o_z)
{
    const float* X; float* O; int D;
    if (blockIdx.y == 0)      { X = dat; O = o_dat; D = DDAT; }
    else if (blockIdx.y == 1) { X = rec; O = o_rec; D = DDAT; }
    else                      { X = z;   O = o_z;   D = DLAT; }

    int row = blockIdx.x;
    float s = 0.f;
    for (int k = threadIdx.x; k < D; k += 256) {
        float v = X[(size_t)row * D + k];
        s += v * v;
    }
    __shared__ float sm[256];
    sm[threadIdx.x] = s;
    __syncthreads();
    for (int off = 128; off > 0; off >>= 1) {
        if (threadIdx.x < off) sm[threadIdx.x] += sm[threadIdx.x + off];
        __syncthreads();
    }
    if (threadIdx.x == 0) O[row] = sm[0];
}

// ---------------------------------------------------------------------------
// MFMA pairwise-phi sum, REG-STAGED (fp32 global -> bf16 regs -> LDS).
// sum over 128x128 tile of rsqrt(alpha + beta*max(a2[i]+b2[j]-2*dot, 0)).
// grid = (64,64), block = 256 (4 waves, each a 64x64 subtile = 4x4 frags of
// mfma_f32_16x16x32_bf16, BK=32). A/B fp32 row-major, leading dim D (no pad;
// K tail zero-filled in registers). sym=1: bx<by blocks write 0; off-diag x2.
// ---------------------------------------------------------------------------
__global__ __launch_bounds__(256, 2)
void pair_mfma_kernel(const float* __restrict__ A,
                      const float* __restrict__ B,
                      const float* __restrict__ a2,
                      const float* __restrict__ b2,
                      int D, float alpha, float beta, int sym,
                      double* __restrict__ part)
{
    const int bx = blockIdx.x;   // j tile
    const int by = blockIdx.y;   // i tile
    const int t  = threadIdx.x;
    if (sym && bx < by) {
        if (t == 0) part[(size_t)by * NBT + bx] = 0.0;
        return;
    }
    const int lane = t & 63;
    const int wave = t >> 6;
    const int wm = wave >> 1;    // wave row (0..1)
    const int wn = wave & 1;     // wave col (0..1)
    const int i0 = by * TILE;
    const int j0 = bx * TILE;

    // LDS tiles: [128 rows][32 k] bf16, row-major linear.
    __shared__ __align__(16) unsigned short As[TILE * 32];
    __shared__ __align__(16) unsigned short Bs[TILE * 32];

    f32x4 acc[4][4] = {};

    for (int k0 = 0; k0 < D; k0 += 32) {
        __syncthreads();   // previous iteration's fragment reads done

        // Stage: 512 chunks of 8 bf16 per matrix; 2 chunks/thread/matrix.
        // chunk g -> row g>>2, k-offset (g&3)*8; LDS short offset g*8.
#pragma unroll
        for (int s = 0; s < 2; ++s) {
            const int g   = s * 256 + t;
            const int row = g >> 2;
            const int kb  = k0 + (g & 3) * 8;

            float va[8], vb[8];
            const float* srcA = &A[(size_t)(i0 + row) * D + kb];
            const float* srcB = &B[(size_t)(j0 + row) * D + kb];
            if (kb + 8 <= D) {
                float4 a0 = *reinterpret_cast<const float4*>(srcA);
                float4 a1 = *reinterpret_cast<const float4*>(srcA + 4);
                va[0]=a0.x; va[1]=a0.y; va[2]=a0.z; va[3]=a0.w;
                va[4]=a1.x; va[5]=a1.y; va[6]=a1.z; va[7]=a1.w;
                float4 b0 = *reinterpret_cast<const float4*>(srcB);
                float4 b1 = *reinterpret_cast<const float4*>(srcB + 4);
                vb[0]=b0.x; vb[1]=b0.y; vb[2]=b0.z; vb[3]=b0.w;
                vb[4]=b1.x; vb[5]=b1.y; vb[6]=b1.z; vb[7]=b1.w;
            } else {
#pragma unroll
                for (int c = 0; c < 8; ++c) {
                    va[c] = (kb + c < D) ? srcA[c] : 0.f;
                    vb[c] = (kb + c < D) ? srcB[c] : 0.f;
                }
            }
            bf16x8 pa, pb;
#pragma unroll
            for (int c = 0; c < 8; ++c) {
                __hip_bfloat16 ha = __float2bfloat16(va[c]);
                __hip_bfloat16 hb = __float2bfloat16(vb[c]);
                pa[c] = *reinterpret_cast<short*>(&ha);
                pb[c] = *reinterpret_cast<short*>(&hb);
            }
            *reinterpret_cast<bf16x8*>(&As[g * 8]) = pa;
            *reinterpret_cast<bf16x8*>(&Bs[g * 8]) = pb;
        }
        __syncthreads();   // staged data visible to all waves

        // Fragment reads: A/B-operand lane layout: row = lane&15,
        // k-group = lane>>4 (8 bf16 each). [m92-verified structure]
        const int lr = lane & 15;
        const int kg = lane >> 4;
        bf16x8 af[4], bfr[4];
#pragma unroll
        for (int m = 0; m < 4; ++m)
            af[m] = *reinterpret_cast<const bf16x8*>(
                &As[(wm * 64 + m * 16 + lr) * 32 + kg * 8]);
#pragma unroll
        for (int n = 0; n < 4; ++n)
            bfr[n] = *reinterpret_cast<const bf16x8*>(
                &Bs[(wn * 64 + n * 16 + lr) * 32 + kg * 8]);
#pragma unroll
        for (int m = 0; m < 4; ++m)
#pragma unroll
            for (int n = 0; n < 4; ++n)
                acc[m][n] = __builtin_amdgcn_mfma_f32_16x16x32_bf16(
                    af[m], bfr[n], acc[m][n], 0, 0, 0);
    }

    // Epilogue: C/D layout col = lane&15, row = (lane>>4)*4 + q  [m89/m91]
    float lsum = 0.f;
    const int cr = lane >> 4;
    const int cc = lane & 15;
#pragma unroll
    for (int m = 0; m < 4; ++m) {
#pragma unroll
        for (int n = 0; n < 4; ++n) {
#pragma unroll
            for (int q = 0; q < 4; ++q) {
                const int gi = i0 + wm * 64 + m * 16 + cr * 4 + q;
                const int gj = j0 + wn * 64 + n * 16 + cc;
                float d = a2[gi] + b2[gj] - 2.f * acc[m][n][q];
                d = fmaxf(d, 0.f);
                float x = alpha + beta * d;
                float r = __frsqrt_rn(x);
                r = r * (1.5f - 0.5f * x * r * r);   // one Newton step
                lsum += r;
            }
        }
    }
    if (sym && bx > by) lsum *= 2.f;   // upper off-diagonal counts twice

    __shared__ float red[256];
    red[t] = lsum;
    __syncthreads();
    for (int off = 128; off > 0; off >>= 1) {
        if (t < off) red[t] += red[t + off];
        __syncthreads();
    }
    if (t == 0) part[(size_t)by * NBT + bx] = (double)red[0];
}

// ---------------------------------------------------------------------------
// Final reduction + scalar math. One block of 256 threads.
// (verbatim from round-1 passing kernel, NPARTS=4096)
// ---------------------------------------------------------------------------
__global__ void finalize_kernel(const double* __restrict__ parts,
                                const float* __restrict__ z2,
                                float* __restrict__ out)
{
    const int tid = threadIdx.x;
    double s0 = 0, s1 = 0, s2 = 0, s3 = 0, s4 = 0;
    for (int i = tid; i < NPARTS; i += 256) {
        s0 += parts[i];
        s1 += parts[NPARTS + i];
        s2 += parts[2 * NPARTS + i];
        s3 += parts[3 * NPARTS + i];
    }
    for (int i = tid; i < NROWS; i += 256) s4 += (double)z2[i];

    __shared__ double sm[256];
    double tot[5];
    double loc[5] = { s0, s1, s2, s3, s4 };
    for (int j = 0; j < 5; ++j) {
        sm[tid] = loc[j];
        __syncthreads();
        for (int off = 128; off > 0; off >>= 1) {
            if (tid < off) sm[tid] += sm[tid + off];
            __syncthreads();
        }
        tot[j] = sm[0];
        __syncthreads();
    }

    if (tid == 0) {
        const double Nn = (double)NROWS;
        const double n2 = Nn * Nn;
        const double y  = pow(4.0 / (3.0 * Nn), 0.4);

        double A = tot[0] / n2;
        double B = tot[1] / n2;
        double C = tot[2] / n2;
        double T = 1.0 / (2.0 * sqrt(M_PI * y));
        double loss_rec = log(T * (A + B - 2.0 * C));

        double An = tot[3] / n2;
        double B1 = tot[4];
        double Bn = 2.0 / sqrt(y + 0.5 + B1 / 125.0);
        double loss_norm = log(1.0 / sqrt(1.0 + y) + An - Bn);

        out[0] = (float)(loss_rec + loss_norm);
    }
}

// ---------------------------------------------------------------------------
extern "C" void kernel_launch(void* const* d_in, const int* in_sizes, int n_in,
                              void* d_out, int out_size, void* d_ws, size_t ws_size,
                              hipStream_t stream)
{
    const float* data = (const float*)d_in[0];
    const float* rec  = (const float*)d_in[1];
    const float* z    = (const float*)d_in[2];
    float* out = (float*)d_out;

    // Workspace: parts (4*4096 doubles = 128 KB) + 3*8192 floats (96 KB).
    // Total ~230 KB — below the ws footprint proven available in round 1.
    char* ws = (char*)d_ws;
    double* parts = (double*)ws;
    float*  a2d   = (float*)(parts + 4 * (size_t)NPARTS);
    float*  a2r   = a2d + NROWS;
    float*  a2z   = a2r + NROWS;

    hipMemsetAsync(parts, 0, 4 * (size_t)NPARTS * sizeof(double), stream);

    rownorm_kernel<<<dim3(NROWS, 3), 256, 0, stream>>>(
        data, rec, z, a2d, a2r, a2z);

    const double y = pow(4.0 / (3.0 * (double)NROWS), 0.4);
    const float beta_s = (float)(1.0 / (1565.0 * y));   // 2*DDAT-3 = 1565

    dim3 grid(NBT, NBT);
    // A: data-data (symmetric)
    pair_mfma_kernel<<<grid, 256, 0, stream>>>(
        data, data, a2d, a2d, DDAT, 1.0f, beta_s, 1, parts);
    // B: recon-recon (symmetric)
    pair_mfma_kernel<<<grid, 256, 0, stream>>>(
        rec, rec, a2r, a2r, DDAT, 1.0f, beta_s, 1, parts + NPARTS);
    // C: data-recon (full)
    pair_mfma_kernel<<<grid, 256, 0, stream>>>(
        data, rec, a2d, a2r, DDAT, 1.0f, beta_s, 0, parts + 2 * NPARTS);
    // normality: z-z (symmetric), phi = rsqrt(y + dist/125)
    pair_mfma_kernel<<<grid, 256, 0, stream>>>(
        z, z, a2z, a2z, DLAT, (float)y, 1.0f / 125.0f, 1, parts + 3 * NPARTS);

    finalize_kernel<<<1, 256, 0, stream>>>(parts, a2z, out);
}

// Round 5
// 363.100 us; speedup vs baseline: 7.8602x; 1.4582x over previous
//
#include <hip/hip_runtime.h>
#include <hip/hip_bf16.h>
#include <math.h>

// Problem constants
#define NROWS 8192
#define DDAT  784
#define LDK_D 800            // padded K for fast path (multiple of 32)
#define DLAT  64
#define TILE  128            // output tile per block
#define NBT   (NROWS / TILE) // 64 tiles per dim
#define NPARTS (NBT * NBT)   // 4096 partial slots per matrix

typedef __attribute__((ext_vector_type(8))) short bf16x8;
typedef __attribute__((ext_vector_type(4))) float f32x4;

__device__ __forceinline__ void gload_lds16(const void* g, void* l) {
    __builtin_amdgcn_global_load_lds(
        (const __attribute__((address_space(1))) unsigned int*)g,
        (__attribute__((address_space(3))) unsigned int*)l,
        16 /*bytes*/, 0, 0);
}

// ---------------------------------------------------------------------------
// Row squared-norms (fp32 exact). grid = (8192, 3), block = 256.  [slow path]
// ---------------------------------------------------------------------------
__global__ void rownorm_kernel(const float* __restrict__ dat,
                               const float* __restrict__ rec,
                               const float* __restrict__ z,
                               float* __restrict__ o_dat,
                               float* __restrict__ o_rec,
                               float* __restrict__ o_z)
{
    const float* X; float* O; int D;
    if (blockIdx.y == 0)      { X = dat; O = o_dat; D = DDAT; }
    else if (blockIdx.y == 1) { X = rec; O = o_rec; D = DDAT; }
    else                      { X = z;   O = o_z;   D = DLAT; }

    int row = blockIdx.x;
    float s = 0.f;
    for (int k = threadIdx.x; k < D; k += 256) {
        float v = X[(size_t)row * D + k];
        s += v * v;
    }
    __shared__ float sm[256];
    sm[threadIdx.x] = s;
    __syncthreads();
    for (int off = 128; off > 0; off >>= 1) {
        if (threadIdx.x < off) sm[threadIdx.x] += sm[threadIdx.x + off];
        __syncthreads();
    }
    if (threadIdx.x == 0) O[row] = sm[0];
}

// ---------------------------------------------------------------------------
// [fast path] fp32 -> bf16 (zero-padded to LDK) + exact fp32 row norms, fused.
// grid = (8192, 3), block = 256.
// ---------------------------------------------------------------------------
__global__ void convert_kernel(const float* __restrict__ dat,
                               const float* __restrict__ rec,
                               const float* __restrict__ z,
                               unsigned short* __restrict__ dat_bf,
                               unsigned short* __restrict__ rec_bf,
                               unsigned short* __restrict__ z_bf,
                               float* __restrict__ a2d,
                               float* __restrict__ a2r,
                               float* __restrict__ a2z)
{
    const float* X; unsigned short* O; float* N2; int D, LDK;
    if (blockIdx.y == 0)      { X = dat; O = dat_bf; N2 = a2d; D = DDAT; LDK = LDK_D; }
    else if (blockIdx.y == 1) { X = rec; O = rec_bf; N2 = a2r; D = DDAT; LDK = LDK_D; }
    else                      { X = z;   O = z_bf;   N2 = a2z; D = DLAT; LDK = DLAT; }

    const int row = blockIdx.x;
    float s = 0.f;
    for (int k = threadIdx.x; k < LDK; k += 256) {
        float v = (k < D) ? X[(size_t)row * D + k] : 0.f;
        __hip_bfloat16 h = __float2bfloat16(v);
        O[(size_t)row * LDK + k] = *reinterpret_cast<unsigned short*>(&h);
        s += v * v;
    }
    __shared__ float sm[256];
    sm[threadIdx.x] = s;
    __syncthreads();
    for (int off = 128; off > 0; off >>= 1) {
        if (threadIdx.x < off) sm[threadIdx.x] += sm[threadIdx.x + off];
        __syncthreads();
    }
    if (threadIdx.x == 0) N2[row] = sm[0];
}

// ---------------------------------------------------------------------------
// [fast path] MFMA pairwise-phi sum from pre-converted bf16.
// global_load_lds staging into DOUBLE-BUFFERED LDS, ONE barrier per K-step:
// iter k stages buf[k&1]; a wave reaches its stage of buf[p] (iter k) only
// after barrier k-1, which requires all waves' iter-(k-2) reads of buf[p] to
// be drained -> race-free by parity. Explicit vmcnt(0) before the barrier
// guarantees staged data is visible regardless of compiler waitcnt policy.
// grid = (64,64), block = 256 (4 waves, 64x64 subtile each, 4x4 frags of
// mfma_f32_16x16x32_bf16, BK=32). LDK multiple of 32, zero-padded.
// ---------------------------------------------------------------------------
__global__ __launch_bounds__(256, 2)
void pair_mfma_fast(const unsigned short* __restrict__ A,
                    const unsigned short* __restrict__ B,
                    const float* __restrict__ a2,
                    const float* __restrict__ b2,
                    int LDK, float alpha, float beta, int sym,
                    double* __restrict__ part)
{
    const int bx = blockIdx.x;   // j tile
    const int by = blockIdx.y;   // i tile
    const int t  = threadIdx.x;
    if (sym && bx < by) {
        if (t == 0) part[(size_t)by * NBT + bx] = 0.0;
        return;
    }
    const int lane = t & 63;
    const int wave = t >> 6;
    const int wm = wave >> 1;    // wave row (0..1)
    const int wn = wave & 1;     // wave col (0..1)
    const int i0 = by * TILE;
    const int j0 = bx * TILE;

    // Double-buffered LDS tiles: [2][128 rows][32 k] bf16, linear, 16B-aligned.
    __shared__ __align__(16) unsigned short As[2][TILE * 32];
    __shared__ __align__(16) unsigned short Bs[2][TILE * 32];

    f32x4 acc[4][4] = {};

    int p = 0;
    for (int k0 = 0; k0 < LDK; k0 += 32, p ^= 1) {
        // Stage A and B tiles into buf[p]: 512 x 16B chunks per matrix;
        // chunk g -> row g>>2, 16B-half g&3; LDS byte offset g*16.
        // Wave-uniform LDS base + lane*16; per-lane global addresses.
#pragma unroll
        for (int s = 0; s < 2; ++s) {
            const int g    = s * 256 + t;
            const int row  = g >> 2;
            const int half = g & 3;
            const int ldsbase = (s * 256 + wave * 64) * 8;   // in shorts
            gload_lds16(&A[(size_t)(i0 + row) * LDK + k0 + half * 8], &As[p][ldsbase]);
            gload_lds16(&B[(size_t)(j0 + row) * LDK + k0 + half * 8], &Bs[p][ldsbase]);
        }
        // Force-drain this wave's staging loads, pin ordering, then barrier.
        asm volatile("s_waitcnt vmcnt(0)" ::: "memory");
        __builtin_amdgcn_sched_barrier(0);
        __syncthreads();

        const int lr = lane & 15;
        const int kg = lane >> 4;
        bf16x8 af[4], bfr[4];
#pragma unroll
        for (int m = 0; m < 4; ++m)
            af[m] = *reinterpret_cast<const bf16x8*>(
                &As[p][(wm * 64 + m * 16 + lr) * 32 + kg * 8]);
#pragma unroll
        for (int n = 0; n < 4; ++n)
            bfr[n] = *reinterpret_cast<const bf16x8*>(
                &Bs[p][(wn * 64 + n * 16 + lr) * 32 + kg * 8]);
#pragma unroll
        for (int m = 0; m < 4; ++m)
#pragma unroll
            for (int n = 0; n < 4; ++n)
                acc[m][n] = __builtin_amdgcn_mfma_f32_16x16x32_bf16(
                    af[m], bfr[n], acc[m][n], 0, 0, 0);
    }

    // Epilogue: C/D layout col = lane&15, row = (lane>>4)*4 + q  [m89/m91]
    float lsum = 0.f;
    const int cr = lane >> 4;
    const int cc = lane & 15;
#pragma unroll
    for (int m = 0; m < 4; ++m) {
#pragma unroll
        for (int n = 0; n < 4; ++n) {
#pragma unroll
            for (int q = 0; q < 4; ++q) {
                const int gi = i0 + wm * 64 + m * 16 + cr * 4 + q;
                const int gj = j0 + wn * 64 + n * 16 + cc;
                float d = a2[gi] + b2[gj] - 2.f * acc[m][n][q];
                d = fmaxf(d, 0.f);
                float x = alpha + beta * d;
                float r = __frsqrt_rn(x);
                r = r * (1.5f - 0.5f * x * r * r);   // one Newton step
                lsum += r;
            }
        }
    }
    if (sym && bx > by) lsum *= 2.f;

    __shared__ float red[256];
    red[t] = lsum;
    __syncthreads();
    for (int off = 128; off > 0; off >>= 1) {
        if (t < off) red[t] += red[t + off];
        __syncthreads();
    }
    if (t == 0) part[(size_t)by * NBT + bx] = (double)red[0];
}

// ---------------------------------------------------------------------------
// [slow path fallback] round-3 verified reg-staged kernel, verbatim.
// ---------------------------------------------------------------------------
__global__ __launch_bounds__(256, 2)
void pair_mfma_kernel(const float* __restrict__ A,
                      const float* __restrict__ B,
                      const float* __restrict__ a2,
                      const float* __restrict__ b2,
                      int D, float alpha, float beta, int sym,
                      double* __restrict__ part)
{
    const int bx = blockIdx.x;
    const int by = blockIdx.y;
    const int t  = threadIdx.x;
    if (sym && bx < by) {
        if (t == 0) part[(size_t)by * NBT + bx] = 0.0;
        return;
    }
    const int lane = t & 63;
    const int wave = t >> 6;
    const int wm = wave >> 1;
    const int wn = wave & 1;
    const int i0 = by * TILE;
    const int j0 = bx * TILE;

    __shared__ __align__(16) unsigned short As[TILE * 32];
    __shared__ __align__(16) unsigned short Bs[TILE * 32];

    f32x4 acc[4][4] = {};

    for (int k0 = 0; k0 < D; k0 += 32) {
        __syncthreads();
#pragma unroll
        for (int s = 0; s < 2; ++s) {
            const int g   = s * 256 + t;
            const int row = g >> 2;
            const int kb  = k0 + (g & 3) * 8;

            float va[8], vb[8];
            const float* srcA = &A[(size_t)(i0 + row) * D + kb];
            const float* srcB = &B[(size_t)(j0 + row) * D + kb];
            if (kb + 8 <= D) {
                float4 a0 = *reinterpret_cast<const float4*>(srcA);
                float4 a1 = *reinterpret_cast<const float4*>(srcA + 4);
                va[0]=a0.x; va[1]=a0.y; va[2]=a0.z; va[3]=a0.w;
                va[4]=a1.x; va[5]=a1.y; va[6]=a1.z; va[7]=a1.w;
                float4 b0 = *reinterpret_cast<const float4*>(srcB);
                float4 b1 = *reinterpret_cast<const float4*>(srcB + 4);
                vb[0]=b0.x; vb[1]=b0.y; vb[2]=b0.z; vb[3]=b0.w;
                vb[4]=b1.x; vb[5]=b1.y; vb[6]=b1.z; vb[7]=b1.w;
            } else {
#pragma unroll
                for (int c = 0; c < 8; ++c) {
                    va[c] = (kb + c < D) ? srcA[c] : 0.f;
                    vb[c] = (kb + c < D) ? srcB[c] : 0.f;
                }
            }
            bf16x8 pa, pb;
#pragma unroll
            for (int c = 0; c < 8; ++c) {
                __hip_bfloat16 ha = __float2bfloat16(va[c]);
                __hip_bfloat16 hb = __float2bfloat16(vb[c]);
                pa[c] = *reinterpret_cast<short*>(&ha);
                pb[c] = *reinterpret_cast<short*>(&hb);
            }
            *reinterpret_cast<bf16x8*>(&As[g * 8]) = pa;
            *reinterpret_cast<bf16x8*>(&Bs[g * 8]) = pb;
        }
        __syncthreads();

        const int lr = lane & 15;
        const int kg = lane >> 4;
        bf16x8 af[4], bfr[4];
#pragma unroll
        for (int m = 0; m < 4; ++m)
            af[m] = *reinterpret_cast<const bf16x8*>(
                &As[(wm * 64 + m * 16 + lr) * 32 + kg * 8]);
#pragma unroll
        for (int n = 0; n < 4; ++n)
            bfr[n] = *reinterpret_cast<const bf16x8*>(
                &Bs[(wn * 64 + n * 16 + lr) * 32 + kg * 8]);
#pragma unroll
        for (int m = 0; m < 4; ++m)
#pragma unroll
            for (int n = 0; n < 4; ++n)
                acc[m][n] = __builtin_amdgcn_mfma_f32_16x16x32_bf16(
                    af[m], bfr[n], acc[m][n], 0, 0, 0);
    }

    float lsum = 0.f;
    const int cr = lane >> 4;
    const int cc = lane & 15;
#pragma unroll
    for (int m = 0; m < 4; ++m) {
#pragma unroll
        for (int n = 0; n < 4; ++n) {
#pragma unroll
            for (int q = 0; q < 4; ++q) {
                const int gi = i0 + wm * 64 + m * 16 + cr * 4 + q;
                const int gj = j0 + wn * 64 + n * 16 + cc;
                float d = a2[gi] + b2[gj] - 2.f * acc[m][n][q];
                d = fmaxf(d, 0.f);
                float x = alpha + beta * d;
                float r = __frsqrt_rn(x);
                r = r * (1.5f - 0.5f * x * r * r);
                lsum += r;
            }
        }
    }
    if (sym && bx > by) lsum *= 2.f;

    __shared__ float red[256];
    red[t] = lsum;
    __syncthreads();
    for (int off = 128; off > 0; off >>= 1) {
        if (t < off) red[t] += red[t + off];
        __syncthreads();
    }
    if (t == 0) part[(size_t)by * NBT + bx] = (double)red[0];
}

// ---------------------------------------------------------------------------
// Final reduction + scalar math. One block of 256 threads.
// ---------------------------------------------------------------------------
__global__ void finalize_kernel(const double* __restrict__ parts,
                                const float* __restrict__ z2,
                                float* __restrict__ out)
{
    const int tid = threadIdx.x;
    double s0 = 0, s1 = 0, s2 = 0, s3 = 0, s4 = 0;
    for (int i = tid; i < NPARTS; i += 256) {
        s0 += parts[i];
        s1 += parts[NPARTS + i];
        s2 += parts[2 * NPARTS + i];
        s3 += parts[3 * NPARTS + i];
    }
    for (int i = tid; i < NROWS; i += 256) s4 += (double)z2[i];

    __shared__ double sm[256];
    double tot[5];
    double loc[5] = { s0, s1, s2, s3, s4 };
    for (int j = 0; j < 5; ++j) {
        sm[tid] = loc[j];
        __syncthreads();
        for (int off = 128; off > 0; off >>= 1) {
            if (tid < off) sm[tid] += sm[tid + off];
            __syncthreads();
        }
        tot[j] = sm[0];
        __syncthreads();
    }

    if (tid == 0) {
        const double Nn = (double)NROWS;
        const double n2 = Nn * Nn;
        const double y  = pow(4.0 / (3.0 * Nn), 0.4);

        double A = tot[0] / n2;
        double B = tot[1] / n2;
        double C = tot[2] / n2;
        double T = 1.0 / (2.0 * sqrt(M_PI * y));
        double loss_rec = log(T * (A + B - 2.0 * C));

        double An = tot[3] / n2;
        double B1 = tot[4];
        double Bn = 2.0 / sqrt(y + 0.5 + B1 / 125.0);
        double loss_norm = log(1.0 / sqrt(1.0 + y) + An - Bn);

        out[0] = (float)(loss_rec + loss_norm);
    }
}

// ---------------------------------------------------------------------------
extern "C" void kernel_launch(void* const* d_in, const int* in_sizes, int n_in,
                              void* d_out, int out_size, void* d_ws, size_t ws_size,
                              hipStream_t stream)
{
    const float* data = (const float*)d_in[0];
    const float* rec  = (const float*)d_in[1];
    const float* z    = (const float*)d_in[2];
    float* out = (float*)d_out;

    // ws layout: [parts 128KB][norms 96KB][dat_bf 13.1MB][rec_bf 13.1MB][z_bf 1MB]
    char* ws = (char*)d_ws;
    double* parts = (double*)ws;
    float*  a2d   = (float*)(parts + 4 * (size_t)NPARTS);
    float*  a2r   = a2d + NROWS;
    float*  a2z   = a2r + NROWS;
    unsigned short* dat_bf = (unsigned short*)(a2z + NROWS);
    unsigned short* rec_bf = dat_bf + (size_t)NROWS * LDK_D;
    unsigned short* z_bf   = rec_bf + (size_t)NROWS * LDK_D;

    const size_t base_need = 4 * (size_t)NPARTS * sizeof(double) + 3 * (size_t)NROWS * sizeof(float);
    const size_t full_need = base_need +
        (2 * (size_t)NROWS * LDK_D + (size_t)NROWS * DLAT) * sizeof(unsigned short);
    const bool fast = (ws_size >= full_need);

    hipMemsetAsync(parts, 0, 4 * (size_t)NPARTS * sizeof(double), stream);

    const double y = pow(4.0 / (3.0 * (double)NROWS), 0.4);
    const float beta_s = (float)(1.0 / (1565.0 * y));   // 2*DDAT-3 = 1565

    dim3 grid(NBT, NBT);

    if (fast) {
        convert_kernel<<<dim3(NROWS, 3), 256, 0, stream>>>(
            data, rec, z, dat_bf, rec_bf, z_bf, a2d, a2r, a2z);
        pair_mfma_fast<<<grid, 256, 0, stream>>>(
            dat_bf, dat_bf, a2d, a2d, LDK_D, 1.0f, beta_s, 1, parts);
        pair_mfma_fast<<<grid, 256, 0, stream>>>(
            rec_bf, rec_bf, a2r, a2r, LDK_D, 1.0f, beta_s, 1, parts + NPARTS);
        pair_mfma_fast<<<grid, 256, 0, stream>>>(
            dat_bf, rec_bf, a2d, a2r, LDK_D, 1.0f, beta_s, 0, parts + 2 * NPARTS);
        pair_mfma_fast<<<grid, 256, 0, stream>>>(
            z_bf, z_bf, a2z, a2z, DLAT, (float)y, 1.0f / 125.0f, 1, parts + 3 * NPARTS);
    } else {
        rownorm_kernel<<<dim3(NROWS, 3), 256, 0, stream>>>(
            data, rec, z, a2d, a2r, a2z);
        pair_mfma_kernel<<<grid, 256, 0, stream>>>(
            data, data, a2d, a2d, DDAT, 1.0f, beta_s, 1, parts);
        pair_mfma_kernel<<<grid, 256, 0, stream>>>(
            rec, rec, a2r, a2r, DDAT, 1.0f, beta_s, 1, parts + NPARTS);
        pair_mfma_kernel<<<grid, 256, 0, stream>>>(
            data, rec, a2d, a2r, DDAT, 1.0f, beta_s, 0, parts + 2 * NPARTS);
        pair_mfma_kernel<<<grid, 256, 0, stream>>>(
            z, z, a2z, a2z, DLAT, (float)y, 1.0f / 125.0f, 1, parts + 3 * NPARTS);
    }

    finalize_kernel<<<1, 256, 0, stream>>>(parts, a2z, out);
}